// Round 3
// baseline (971.537 us; speedup 1.0000x reference)
//
#include <hip/hip_runtime.h>

#define DD 2048
#define SS 8192
#define BB 8
#define TWO_D 4096
#define C_CHAIN 64
#define GRID 512
#define LN_EPS 1e-5f

typedef float f32x4 __attribute__((ext_vector_type(4)));

static __device__ const int g_PZ[7] = {12, 36, 104, 304, 888, 2592, 7568};
static __device__ const int g_PY[7] = {4, 12, 36, 104, 304, 888, 2592};
static __device__ const int g_PX[7] = {2, 4, 12, 36, 104, 304, 888};

extern "C" __global__ __launch_bounds__(256) void mega(
    const float* __restrict__ x,
    const float* __restrict__ a_xz, const float* __restrict__ b_xy, const float* __restrict__ g_x,
    const float* __restrict__ a_wy, const float* __restrict__ b_wx, const float* __restrict__ g_w,
    const float* __restrict__ a_xv, const float* __restrict__ b_wv, const float* __restrict__ g_v,
    const float* __restrict__ gate_w, const float* __restrict__ gate_b,
    const float* __restrict__ ln_w, const float* __restrict__ ln_b,
    float* __restrict__ out, int* ctr, int* ticket, float* ubase)
{
    __shared__ float lds[BB][DD];          // 64 KiB -> 2 blocks/CU; grid 512 = all co-resident
    const int tid = threadIdx.x, lane = tid & 63, wave = tid >> 6;
    const int blk = blockIdx.x;
    const size_t bstr = (size_t)SS * DD;

    if (blk < C_CHAIN) {
        const int colbase = blk * 32 + wave * 8;   // 32 cols per block, 8 per wave
        const int myb = lane & 7, myc = (lane >> 3) & 1;

        for (int it = 0; it < 7; ++it) {
            const int pz = g_PZ[it], py = g_PY[it], px = g_PX[it];
            const float* uY = ubase + (size_t)(it > 0 ? it - 1 : 0) * BB * DD;
            const float* uX = ubase + (size_t)(it > 1 ? it - 2 : 0) * BB * DD;
            const bool lnY = (it >= 1), lnX = (it >= 2);

            // ---- per-block redundant LN stats of u[it-1] (y) and u[it-2] (xp) ----
            if (lnY | lnX) {
                for (int t = wave; t < 16; t += 4) {
                    const bool isY = (t < 8); const int b = t & 7;
                    if (isY ? lnY : lnX) {
                        const float* row = (isY ? uY : uX) + b * DD;
                        float s = 0.f, sq = 0.f;
#pragma unroll
                        for (int i = 0; i < DD / 64; ++i) {
                            const float v = row[lane + 64 * i];
                            s += v; sq += v * v;
                        }
#pragma unroll
                        for (int off = 32; off >= 1; off >>= 1) {
                            s += __shfl_xor(s, off); sq += __shfl_xor(sq, off);
                        }
                        if (lane == 0) {
                            const float mean = s * (1.f / DD);
                            const float var  = sq * (1.f / DD) - mean * mean;
                            lds[0][t * 2]     = mean;
                            lds[0][t * 2 + 1] = rsqrtf(var + LN_EPS);
                        }
                    }
                }
            }
            __syncthreads();
            float ym[8], yrs[8], xm[8], xrs[8];
#pragma unroll
            for (int b = 0; b < 8; ++b) {
                ym[b]  = lnY ? lds[0][b * 2]           : 0.f;
                yrs[b] = lnY ? lds[0][b * 2 + 1]       : 0.f;
                xm[b]  = lnX ? lds[0][(8 + b) * 2]     : 0.f;
                xrs[b] = lnX ? lds[0][(8 + b) * 2 + 1] : 0.f;
            }
            __syncthreads();

            // ---- stage v into LDS ----
            const float* zrow = x + (size_t)pz * DD;
            const float* yraw = x + (size_t)py * DD;
            const float* xraw = x + (size_t)px * DD;
            for (int dd = 0; dd < DD; dd += 256) {
                const int d = dd + tid;
                const float axz = a_xz[d], bxy = b_xy[d], gx  = g_x[d];
                const float awy = a_wy[d], bwx = b_wx[d], gww = g_w[d];
                const float axv = a_xv[d], bwv = b_wv[d], gv  = g_v[d];
                const float lw = ln_w[d], lb = ln_b[d];
#pragma unroll
                for (int b = 0; b < BB; ++b) {
                    const float z  = zrow[(size_t)b * bstr + d];
                    const float y  = lnY ? (uY[b * DD + d] - ym[b]) * yrs[b] * lw + lb
                                         : yraw[(size_t)b * bstr + d];
                    const float xp = lnX ? (uX[b * DD + d] - xm[b]) * xrs[b] * lw + lb
                                         : xraw[(size_t)b * bstr + d];
                    lds[b][d] = axv * (axz * z + bxy * y + gx)
                              + bwv * (awy * y + bwx * xp + gww) + gv;
                }
            }
            __syncthreads();

            // ---- phase A: v-half of the gate dot products ----
            float vpart[4], vm[4];
#pragma unroll
            for (int vb = 0; vb < 4; ++vb) {
                const int d0 = colbase + vb * 2;
                const float* gw0 = gate_w + (size_t)d0 * TWO_D;
                const float* gw1 = gw0 + TWO_D;
                float a0[8], a1[8];
#pragma unroll
                for (int b = 0; b < 8; ++b) { a0[b] = 0.f; a1[b] = 0.f; }
#pragma unroll
                for (int k = 0; k < 8; ++k) {
                    const int j = lane * 4 + k * 256;
                    const float4 w0 = *(const float4*)(gw0 + j);
                    const float4 w1 = *(const float4*)(gw1 + j);
#pragma unroll
                    for (int b = 0; b < 8; ++b) {
                        const float4 vv = *(const float4*)&lds[b][j];
                        a0[b] += w0.x*vv.x + w0.y*vv.y + w0.z*vv.z + w0.w*vv.w;
                        a1[b] += w1.x*vv.x + w1.y*vv.y + w1.z*vv.z + w1.w*vv.w;
                    }
                }
#pragma unroll
                for (int b = 0; b < 8; ++b) {
#pragma unroll
                    for (int off = 32; off >= 1; off >>= 1) {
                        a0[b] += __shfl_xor(a0[b], off);
                        a1[b] += __shfl_xor(a1[b], off);
                    }
                }
                vpart[vb] = myc ? a1[myb] : a0[myb];
                vm[vb]    = lds[myb][d0 + myc];
            }
            __syncthreads();

            // ---- stage z into LDS ----
            for (int dd = 0; dd < 512; dd += 256) {
                const int d4 = dd + tid;
#pragma unroll
                for (int b = 0; b < BB; ++b)
                    ((float4*)&lds[b][0])[d4] = ((const float4*)(zrow + (size_t)b * bstr))[d4];
            }
            __syncthreads();

            // ---- phase B: z-half + gate + u write ----
            float* urow = ubase + (size_t)it * BB * DD;
#pragma unroll
            for (int vb = 0; vb < 4; ++vb) {
                const int d0 = colbase + vb * 2;
                const float* gw0 = gate_w + (size_t)d0 * TWO_D + DD;
                const float* gw1 = gw0 + TWO_D;
                float a0[8], a1[8];
#pragma unroll
                for (int b = 0; b < 8; ++b) { a0[b] = 0.f; a1[b] = 0.f; }
#pragma unroll
                for (int k = 0; k < 8; ++k) {
                    const int j = lane * 4 + k * 256;
                    const float4 w0 = *(const float4*)(gw0 + j);
                    const float4 w1 = *(const float4*)(gw1 + j);
#pragma unroll
                    for (int b = 0; b < 8; ++b) {
                        const float4 zz = *(const float4*)&lds[b][j];
                        a0[b] += w0.x*zz.x + w0.y*zz.y + w0.z*zz.z + w0.w*zz.w;
                        a1[b] += w1.x*zz.x + w1.y*zz.y + w1.z*zz.z + w1.w*zz.w;
                    }
                }
#pragma unroll
                for (int b = 0; b < 8; ++b) {
#pragma unroll
                    for (int off = 32; off >= 1; off >>= 1) {
                        a0[b] += __shfl_xor(a0[b], off);
                        a1[b] += __shfl_xor(a1[b], off);
                    }
                }
                if (lane < 16) {
                    const int d = d0 + myc;
                    const float tot = vpart[vb] + (myc ? a1[myb] : a0[myb]);
                    const float zmv = lds[myb][d];
                    const float gg  = 1.f / (1.f + __expf(-(tot + gate_b[d])));
                    urow[myb * DD + d] = gg * vm[vb] + (1.f - gg) * zmv;
                }
            }

            // ---- barrier over the 64 chain blocks (one-shot counter per iter) ----
            __threadfence();
            __syncthreads();
            if (tid == 0) {
                __hip_atomic_fetch_add(ctr + it, 1, __ATOMIC_ACQ_REL, __HIP_MEMORY_SCOPE_AGENT);
                while (__hip_atomic_load(ctr + it, __ATOMIC_ACQUIRE, __HIP_MEMORY_SCOPE_AGENT) < C_CHAIN) {
                    __builtin_amdgcn_s_sleep(2);
                }
            }
            __syncthreads();
            __threadfence();

            // ---- inject LN(u[it]) row pz into out (blocks 0..7, one batch each) ----
            if (blk < 8) {
                const float* ub = urow + blk * DD;
                float vals[8]; float s = 0.f, sq = 0.f;
#pragma unroll
                for (int i = 0; i < 8; ++i) {
                    const float v = ub[tid + 256 * i];
                    vals[i] = v; s += v; sq += v * v;
                }
#pragma unroll
                for (int off = 32; off >= 1; off >>= 1) {
                    s += __shfl_xor(s, off); sq += __shfl_xor(sq, off);
                }
                if (lane == 0) { lds[0][wave] = s; lds[0][4 + wave] = sq; }
                __syncthreads();
                s  = lds[0][0] + lds[0][1] + lds[0][2] + lds[0][3];
                sq = lds[0][4] + lds[0][5] + lds[0][6] + lds[0][7];
                const float mean = s * (1.f / DD);
                const float var  = sq * (1.f / DD) - mean * mean;
                const float rs   = rsqrtf(var + LN_EPS);
                float* orow = out + (size_t)blk * bstr + (size_t)pz * DD;
#pragma unroll
                for (int i = 0; i < 8; ++i) {
                    const int d = tid + 256 * i;
                    orow[d] = (vals[i] - mean) * rs * ln_w[d] + ln_b[d];
                }
                __syncthreads();
            }
        }
    }

    // ---- copy x -> out, wave-level work-stealing, skip the 7 spine rows ----
    const f32x4* src4 = (const f32x4*)x;
    f32x4* dst4 = (f32x4*)out;
    for (;;) {
        int t;
        if (lane == 0) t = atomicAdd(ticket, 1);
        t = __shfl(t, 0);
        if (t >= 8192) break;                    // 8192 tiles x 8 rows
        const size_t base4 = (size_t)t * 4096;   // 4096 float4 per tile
#pragma unroll
        for (int r8 = 0; r8 < 8; ++r8) {
            const int srow = ((t << 3) + r8) & (SS - 1);
            const bool skip = (srow==12)|(srow==36)|(srow==104)|(srow==304)|
                              (srow==888)|(srow==2592)|(srow==7568);
            if (!skip) {
                const size_t o = base4 + (size_t)r8 * 512 + lane;
#pragma unroll
                for (int kk = 0; kk < 8; ++kk) {
                    const f32x4 v = __builtin_nontemporal_load(&src4[o + kk * 64]);
                    __builtin_nontemporal_store(v, &dst4[o + kk * 64]);
                }
            }
        }
    }
}

extern "C" void kernel_launch(void* const* d_in, const int* in_sizes, int n_in,
                              void* d_out, int out_size, void* d_ws, size_t ws_size,
                              hipStream_t stream)
{
    const float* x      = (const float*)d_in[0];
    const float* a_xz   = (const float*)d_in[1];
    const float* b_xy   = (const float*)d_in[2];
    const float* g_x    = (const float*)d_in[3];
    const float* a_wy   = (const float*)d_in[4];
    const float* b_wx   = (const float*)d_in[5];
    const float* g_w    = (const float*)d_in[6];
    const float* a_xv   = (const float*)d_in[7];
    const float* b_wv   = (const float*)d_in[8];
    const float* g_v    = (const float*)d_in[9];
    const float* gate_w = (const float*)d_in[10];
    const float* gate_b = (const float*)d_in[11];
    const float* ln_w   = (const float*)d_in[12];
    const float* ln_b   = (const float*)d_in[13];
    float* out = (float*)d_out;

    int* ctr    = (int*)d_ws;            // ctr[0..6] barrier counters
    int* ticket = ctr + 7;               // copy work-steal ticket
    float* ubase = (float*)d_ws + 64;    // 7 x [8][2048] u buffers (pre-LN)

    hipMemsetAsync(d_ws, 0, 64, stream); // reset counters + ticket each call

    hipLaunchKernelGGL(mega, dim3(GRID), dim3(256), 0, stream,
                       x, a_xz, b_xy, g_x, a_wy, b_wx, g_w,
                       a_xv, b_wv, g_v, gate_w, gate_b, ln_w, ln_b,
                       out, ctr, ticket, ubase);
}

// Round 4
// 548.163 us; speedup vs baseline: 1.7724x; 1.7724x over previous
//
#include <hip/hip_runtime.h>

#define DD 2048
#define SS 8192
#define BB 8
#define TWO_D 4096
#define LN_EPS 1e-5f
#define NCHAIN 256          // chain blocks (8 cols each = 2048 cols)
#define NCOPY 1024          // copy blocks per launch (8 rows each)

typedef float f32x4 __attribute__((ext_vector_type(4)));

static __device__ const int g_PZ[7] = {12, 36, 104, 304, 888, 2592, 7568};
static __device__ const int g_PY[7] = {4, 12, 36, 104, 304, 888, 2592};
static __device__ const int g_PX[7] = {2, 4, 12, 36, 104, 304, 888};

__device__ __forceinline__ bool is_spine(int r) {
    return (r==12)|(r==36)|(r==104)|(r==304)|(r==888)|(r==2592)|(r==7568);
}

extern "C" __global__ __launch_bounds__(256) void fused(
    int it,
    const float* __restrict__ x,
    const float* __restrict__ a_xz, const float* __restrict__ b_xy, const float* __restrict__ g_x,
    const float* __restrict__ a_wy, const float* __restrict__ b_wx, const float* __restrict__ g_w,
    const float* __restrict__ a_xv, const float* __restrict__ b_wv, const float* __restrict__ g_v,
    const float* __restrict__ gate_w, const float* __restrict__ gate_b,
    const float* __restrict__ ln_w, const float* __restrict__ ln_b,
    float* __restrict__ out, float* __restrict__ ubase)
{
    __shared__ float lds[BB][DD];          // 64 KiB
    const int tid = threadIdx.x, lane = tid & 63, wave = tid >> 6;
    const int blk = blockIdx.x;
    const size_t bstr = (size_t)SS * DD;

    // ------------------------------------------------------------------
    // Copy role: blocks [NCHAIN, NCHAIN+NCOPY) copy slice `it` of x->out.
    // Flat row space: 65536 rows of 2048 floats; slice = 8192 rows.
    // ------------------------------------------------------------------
    if (blk >= NCHAIN) {
        const int cb = blk - NCHAIN;               // 0..1023
        const f32x4* src4 = (const f32x4*)x;
        f32x4* dst4 = (f32x4*)out;
        for (int rr = wave; rr < 8; rr += 4) {
            const int row  = it * 8192 + cb * 8 + rr;   // flat (b,s) row
            const int srow = row & (SS - 1);
            if (is_spine(srow)) continue;
            const f32x4* s = src4 + (size_t)row * 512;
            f32x4*       d = dst4 + (size_t)row * 512;
#pragma unroll
            for (int k = 0; k < 8; ++k)
                d[lane + 64 * k] = s[lane + 64 * k];
        }
        return;
    }

    // ------------------------------------------------------------------
    // Chain role.
    //   it in [0,7): compute u[it] into ws; blocks 0-7 inject LN(u[it-1]).
    //   it == 7   : blocks 0-7 inject LN(u[6]) only.
    // ------------------------------------------------------------------
    const bool lnY = (it >= 1), lnX = (it >= 2) && (it < 7);
    const float* uY = ubase + (size_t)(it > 0 ? it - 1 : 0) * BB * DD;
    const float* uX = ubase + (size_t)(it > 1 ? it - 2 : 0) * BB * DD;

    // ---- per-block redundant LN stats of uY (tasks 0-7) and uX (8-15) ----
    if (lnY | lnX) {
        for (int t = wave; t < 16; t += 4) {
            const bool isY = (t < 8); const int b = t & 7;
            if (isY ? lnY : lnX) {
                const f32x4* row = (const f32x4*)((isY ? uY : uX) + b * DD);
                float s = 0.f, sq = 0.f;
#pragma unroll
                for (int i = 0; i < 8; ++i) {
                    const f32x4 v = row[lane + 64 * i];
                    s  += v.x + v.y + v.z + v.w;
                    sq += v.x*v.x + v.y*v.y + v.z*v.z + v.w*v.w;
                }
#pragma unroll
                for (int off = 32; off >= 1; off >>= 1) {
                    s += __shfl_xor(s, off); sq += __shfl_xor(sq, off);
                }
                if (lane == 0) {
                    const float mean = s * (1.f / DD);
                    const float var  = sq * (1.f / DD) - mean * mean;
                    lds[0][t * 2]     = mean;
                    lds[0][t * 2 + 1] = rsqrtf(var + LN_EPS);
                }
            }
        }
    }
    __syncthreads();
    float ym[8], yrs[8], xm[8], xrs[8];
#pragma unroll
    for (int b = 0; b < 8; ++b) {
        ym[b]  = lnY ? lds[0][b * 2]           : 0.f;
        yrs[b] = lnY ? lds[0][b * 2 + 1]       : 0.f;
        xm[b]  = lnX ? lds[0][(8 + b) * 2]     : 0.f;
        xrs[b] = lnX ? lds[0][(8 + b) * 2 + 1] : 0.f;
    }
    __syncthreads();

    // ---- inject LN(u[it-1]) row PZ[it-1] into out (blocks 0-7) ----
    if (lnY && blk < BB) {
        const float* ub = uY + blk * DD;
        float* orow = out + (size_t)blk * bstr + (size_t)g_PZ[it - 1] * DD;
        const float m = ym[blk], rs = yrs[blk];
#pragma unroll
        for (int i = 0; i < 8; ++i) {
            const int d = tid + 256 * i;
            orow[d] = (ub[d] - m) * rs * ln_w[d] + ln_b[d];
        }
    }
    if (it >= 7) return;

    const int pz = g_PZ[it], py = g_PY[it], px = g_PX[it];
    const float* zrow = x + (size_t)pz * DD;
    const float* yraw = x + (size_t)py * DD;
    const float* xraw = x + (size_t)px * DD;

    // ---- stage v into LDS (all 8 batches) ----
    for (int dd = 0; dd < DD; dd += 256) {
        const int d = dd + tid;
        const float axz = a_xz[d], bxy = b_xy[d], gx  = g_x[d];
        const float awy = a_wy[d], bwx = b_wx[d], gww = g_w[d];
        const float axv = a_xv[d], bwv = b_wv[d], gv  = g_v[d];
        const float lw = ln_w[d], lb = ln_b[d];
#pragma unroll
        for (int b = 0; b < BB; ++b) {
            const float z  = zrow[(size_t)b * bstr + d];
            const float y  = lnY ? (uY[b * DD + d] - ym[b]) * yrs[b] * lw + lb
                                 : yraw[(size_t)b * bstr + d];
            const float xp = lnX ? (uX[b * DD + d] - xm[b]) * xrs[b] * lw + lb
                                 : xraw[(size_t)b * bstr + d];
            lds[b][d] = axv * (axz * z + bxy * y + gx)
                      + bwv * (awy * y + bwx * xp + gww) + gv;
        }
    }
    __syncthreads();

    const int d0 = blk * 8 + wave * 2;         // this wave's two output columns
    const int myb = lane & 7, myc = (lane >> 3) & 1;

    // ---- phase A: v-half of gate dot products ----
    const float* gw0a = gate_w + (size_t)d0 * TWO_D;
    const float* gw1a = gw0a + TWO_D;
    float a0[8], a1[8];
#pragma unroll
    for (int b = 0; b < 8; ++b) { a0[b] = 0.f; a1[b] = 0.f; }
    for (int j = lane * 4; j < DD; j += 256) {
        const float4 w0 = *(const float4*)(gw0a + j);
        const float4 w1 = *(const float4*)(gw1a + j);
#pragma unroll
        for (int b = 0; b < 8; ++b) {
            const float4 vv = *(const float4*)&lds[b][j];
            a0[b] += w0.x*vv.x + w0.y*vv.y + w0.z*vv.z + w0.w*vv.w;
            a1[b] += w1.x*vv.x + w1.y*vv.y + w1.z*vv.z + w1.w*vv.w;
        }
    }
    const float vmine = (lane < 16) ? lds[myb][d0 + myc] : 0.f;
    __syncthreads();

    // ---- stage z into LDS ----
    for (int d4 = tid; d4 < 512; d4 += 256) {
#pragma unroll
        for (int b = 0; b < BB; ++b)
            ((f32x4*)&lds[b][0])[d4] = ((const f32x4*)(zrow + (size_t)b * bstr))[d4];
    }
    __syncthreads();

    // ---- phase B: z-half ----
    const float* gw0b = gw0a + DD;
    const float* gw1b = gw1a + DD;
    for (int j = lane * 4; j < DD; j += 256) {
        const float4 w0 = *(const float4*)(gw0b + j);
        const float4 w1 = *(const float4*)(gw1b + j);
#pragma unroll
        for (int b = 0; b < 8; ++b) {
            const float4 zz = *(const float4*)&lds[b][j];
            a0[b] += w0.x*zz.x + w0.y*zz.y + w0.z*zz.z + w0.w*zz.w;
            a1[b] += w1.x*zz.x + w1.y*zz.y + w1.z*zz.z + w1.w*zz.w;
        }
    }
#pragma unroll
    for (int b = 0; b < 8; ++b) {
#pragma unroll
        for (int off = 32; off >= 1; off >>= 1) {
            a0[b] += __shfl_xor(a0[b], off);
            a1[b] += __shfl_xor(a1[b], off);
        }
    }
    if (lane < 16) {
        const int d = d0 + myc;
        const float tot = myc ? a1[myb] : a0[myb];
        const float zmv = lds[myb][d];
        const float gg  = 1.f / (1.f + __expf(-(tot + gate_b[d])));
        ubase[(size_t)it * BB * DD + myb * DD + d] = gg * vmine + (1.f - gg) * zmv;
    }
}

extern "C" void kernel_launch(void* const* d_in, const int* in_sizes, int n_in,
                              void* d_out, int out_size, void* d_ws, size_t ws_size,
                              hipStream_t stream)
{
    const float* x      = (const float*)d_in[0];
    const float* a_xz   = (const float*)d_in[1];
    const float* b_xy   = (const float*)d_in[2];
    const float* g_x    = (const float*)d_in[3];
    const float* a_wy   = (const float*)d_in[4];
    const float* b_wx   = (const float*)d_in[5];
    const float* g_w    = (const float*)d_in[6];
    const float* a_xv   = (const float*)d_in[7];
    const float* b_wv   = (const float*)d_in[8];
    const float* g_v    = (const float*)d_in[9];
    const float* gate_w = (const float*)d_in[10];
    const float* gate_b = (const float*)d_in[11];
    const float* ln_w   = (const float*)d_in[12];
    const float* ln_b   = (const float*)d_in[13];
    float* out = (float*)d_out;
    float* ubase = (float*)d_ws;         // 7 x [8][2048] u buffers (pre-LN)

    for (int it = 0; it < 8; ++it) {
        hipLaunchKernelGGL(fused, dim3(NCHAIN + NCOPY), dim3(256), 0, stream,
                           it, x, a_xz, b_xy, g_x, a_wy, b_wx, g_w,
                           a_xv, b_wv, g_v, gate_w, gate_b, ln_w, ln_b,
                           out, ubase);
    }
}